// Round 1
// baseline (726.433 us; speedup 1.0000x reference)
//
#include <hip/hip_runtime.h>
#include <math.h>

// Problem constants
#define S_LEN 2048
#define HID 4096
#define NH 32
#define NKV 8
#define HD 128
#define QKV_N ((NH + 2*NKV) * HD)   // 6144
#define NQK (NH + NKV)              // 40
static __device__ __constant__ const float SCALE_F = 0.08838834764831845f; // 128^-0.5

typedef __bf16 bf16x8 __attribute__((ext_vector_type(8)));
typedef __bf16 bf16x4 __attribute__((ext_vector_type(4)));
typedef float  f32x4  __attribute__((ext_vector_type(4)));

// ---------- cast fp32 -> bf16 (vectorized) ----------
__global__ void cast_bf16_kernel(const float4* __restrict__ in, __bf16* __restrict__ out, int n4) {
  int i = blockIdx.x * blockDim.x + threadIdx.x;
  if (i >= n4) return;
  float4 v = in[i];
  bf16x4 o = { (__bf16)v.x, (__bf16)v.y, (__bf16)v.z, (__bf16)v.w };
  *(bf16x4*)(out + (size_t)i * 4) = o;
}

// ---------- transpose + cast: in[R][C] fp32 -> out[C][R] bf16 ----------
__global__ void transpose_cast_kernel(const float* __restrict__ in, __bf16* __restrict__ out,
                                      int R, int C) {
  __shared__ float tile[32][33];
  int bx = blockIdx.x * 32;  // col of in
  int by = blockIdx.y * 32;  // row of in
  int tx = threadIdx.x, ty = threadIdx.y;
  for (int i = 0; i < 32; i += 8)
    tile[ty + i][tx] = in[(size_t)(by + ty + i) * C + bx + tx];
  __syncthreads();
  for (int i = 0; i < 32; i += 8)
    out[(size_t)(bx + ty + i) * R + by + tx] = (__bf16)tile[tx][ty + i];
}

// ---------- V transpose: Vt[kvh][d][s] = qkv[s][(NH+NKV)*HD + kvh*HD + d] ----------
__global__ void transpose_v_kernel(const __bf16* __restrict__ qkv, __bf16* __restrict__ Vt) {
  __shared__ __bf16 tile[32][33];
  int kvh = blockIdx.z;
  int sb = blockIdx.x * 32;
  int db = blockIdx.y * 32;
  int tx = threadIdx.x, ty = threadIdx.y;
  const __bf16* src = qkv + (size_t)(NH + NKV) * HD + (size_t)kvh * HD;
  for (int i = 0; i < 32; i += 8)
    tile[ty + i][tx] = src[(size_t)(sb + ty + i) * QKV_N + db + tx];
  __syncthreads();
  for (int i = 0; i < 32; i += 8)
    Vt[((size_t)kvh * HD + db + ty + i) * S_LEN + sb + tx] = tile[tx][ty + i];
}

// ---------- RoPE: split qkv -> Qr [S][NH][HD], Kr [S][NKV][HD] with rotation ----------
__global__ void rope_kernel(const __bf16* __restrict__ qkv, const int* __restrict__ pos,
                            __bf16* __restrict__ Qr, __bf16* __restrict__ Kr) {
  int idx = blockIdx.x * blockDim.x + threadIdx.x;
  int half = idx & 63;         // 0..63
  int t = idx >> 6;
  int hh = t % NQK;
  int s = t / NQK;
  if (s >= S_LEN) return;
  float p = (float)pos[s];
  float inv_freq = powf(10000.0f, -(float)half / 64.0f);
  float ang = p * inv_freq;
  float cs = cosf(ang), sn = sinf(ang);
  const __bf16* src; __bf16* dst;
  if (hh < NH) {
    src = qkv + (size_t)s * QKV_N + (size_t)hh * HD;
    dst = Qr + ((size_t)s * NH + hh) * HD;
  } else {
    int kh = hh - NH;
    src = qkv + (size_t)s * QKV_N + (size_t)NH * HD + (size_t)kh * HD;
    dst = Kr + ((size_t)s * NKV + kh) * HD;
  }
  float x1 = (float)src[half], x2 = (float)src[half + 64];
  dst[half]      = (__bf16)(x1 * cs - x2 * sn);
  dst[half + 64] = (__bf16)(x2 * cs + x1 * sn);
}

// ---------- bf16 MFMA GEMM: C[M][N] = A[M][K] @ Bt[N][K]^T ----------
// 128x128 tile, BK=32, 4 waves in 2x2, each wave 4x4 16x16 tiles.
// MFMA 16x16x32 bf16. A-frag: m=lane&15, k=quad*8+j. B-frag: n=lane&15, k=quad*8+j.
// C/D layout (verified m89/m91): col=lane&15, row=quad*4+reg.
template <typename OutT>
__global__ __launch_bounds__(256) void gemm_bt_kernel(const __bf16* __restrict__ A,
                                                      const __bf16* __restrict__ Bt,
                                                      OutT* __restrict__ C,
                                                      int M, int N, int K) {
  __shared__ __bf16 As[128 * 32];
  __shared__ __bf16 Bs[128 * 32];
  const int tid = threadIdx.x;
  const int lane = tid & 63;
  const int wave = tid >> 6;
  const int quad = lane >> 4;
  const int l16 = lane & 15;
  const int wm = (wave >> 1) * 64;
  const int wn = (wave & 1) * 64;
  const size_t bm = (size_t)blockIdx.y * 128;
  const size_t bn = (size_t)blockIdx.x * 128;

  f32x4 acc[4][4] = {};

  for (int k0 = 0; k0 < K; k0 += 32) {
    for (int it = 0; it < 2; ++it) {
      int c = it * 256 + tid;          // chunk 0..511, 16B each
      int row = c >> 2, kc = c & 3;
      *(uint4*)&As[c * 8] = *(const uint4*)&A[(bm + row) * (size_t)K + k0 + kc * 8];
      *(uint4*)&Bs[c * 8] = *(const uint4*)&Bt[(bn + row) * (size_t)K + k0 + kc * 8];
    }
    __syncthreads();
    bf16x8 af[4], bfr[4];
    for (int i = 0; i < 4; ++i) af[i]  = *(const bf16x8*)&As[(wm + i * 16 + l16) * 32 + quad * 8];
    for (int j = 0; j < 4; ++j) bfr[j] = *(const bf16x8*)&Bs[(wn + j * 16 + l16) * 32 + quad * 8];
    for (int i = 0; i < 4; ++i)
      for (int j = 0; j < 4; ++j)
        acc[i][j] = __builtin_amdgcn_mfma_f32_16x16x32_bf16(af[i], bfr[j], acc[i][j], 0, 0, 0);
    __syncthreads();
  }
  for (int i = 0; i < 4; ++i)
    for (int j = 0; j < 4; ++j)
      for (int r = 0; r < 4; ++r) {
        size_t row = bm + wm + i * 16 + quad * 4 + r;
        size_t col = bn + wn + j * 16 + l16;
        C[row * (size_t)N + col] = (OutT)acc[i][j][r];
      }
}

// ---------- flash attention (causal, GQA) ----------
// Grid: (NH, S/64). Block: 256 (4 waves). Wave w handles queries q0+16w .. q0+16w+15.
// Per iter: 32 keys. QK^T: 8 MFMA; PV: 8 MFMA. P transits LDS (C-layout -> A-layout).
__global__ __launch_bounds__(256) void attn_kernel(const __bf16* __restrict__ Qr,
                                                   const __bf16* __restrict__ Kr,
                                                   const __bf16* __restrict__ Vt,
                                                   __bf16* __restrict__ O) {
  __shared__ __bf16 Ks[32 * 128];      // [key][d]
  __shared__ __bf16 Vs[128 * 32];      // [d][key]
  __shared__ __bf16 Ps[4][16 * 32];    // per-wave P: [q][key]
  const int h = blockIdx.x;
  const int qb = blockIdx.y;
  const int kvh = h >> 2;              // REP = 4
  const int tid = threadIdx.x;
  const int lane = tid & 63, wave = tid >> 6;
  const int quad = lane >> 4, l16 = lane & 15;
  const int q0 = qb * 64;
  const int qrow = q0 + wave * 16;

  bf16x8 qf[4];
  {
    const __bf16* qp = Qr + (size_t)(qrow + l16) * (NH * HD) + (size_t)h * HD + quad * 8;
    for (int kk = 0; kk < 4; ++kk) qf[kk] = *(const bf16x8*)(qp + kk * 32);
  }
  f32x4 oacc[8] = {};
  float m_i[4], l_i[4];
  for (int r = 0; r < 4; ++r) { m_i[r] = -INFINITY; l_i[r] = 0.0f; }

  for (int kb = 0; kb < q0 + 64; kb += 32) {
    for (int c = tid; c < 512; c += 256) {       // K block: 32x128
      int row = c >> 4, c8 = c & 15;
      *(uint4*)&Ks[row * 128 + c8 * 8] =
        *(const uint4*)&Kr[(size_t)(kb + row) * (NKV * HD) + (size_t)kvh * HD + c8 * 8];
    }
    for (int c = tid; c < 512; c += 256) {       // V^T block: 128x32
      int d = c >> 2, c8 = c & 3;
      *(uint4*)&Vs[d * 32 + c8 * 8] =
        *(const uint4*)&Vt[((size_t)kvh * HD + d) * S_LEN + kb + c8 * 8];
    }
    __syncthreads();

    f32x4 sc[2] = {};
    for (int jt = 0; jt < 2; ++jt)
      for (int kk = 0; kk < 4; ++kk) {
        bf16x8 kf = *(const bf16x8*)&Ks[(jt * 16 + l16) * 128 + kk * 32 + quad * 8];
        sc[jt] = __builtin_amdgcn_mfma_f32_16x16x32_bf16(qf[kk], kf, sc[jt], 0, 0, 0);
      }

    float p0[4], p1[4];
    for (int r = 0; r < 4; ++r) {
      int q = qrow + quad * 4 + r;
      float s0 = (kb + l16 <= q)      ? sc[0][r] * SCALE_F : -INFINITY;
      float s1 = (kb + 16 + l16 <= q) ? sc[1][r] * SCALE_F : -INFINITY;
      float mx = fmaxf(s0, s1);
      for (int off = 8; off >= 1; off >>= 1) mx = fmaxf(mx, __shfl_xor(mx, off, 64));
      float mnew = fmaxf(m_i[r], mx);
      float alpha = __expf(m_i[r] - mnew);   // m_i=-inf first iter -> alpha=0
      p0[r] = __expf(s0 - mnew);
      p1[r] = __expf(s1 - mnew);
      float sum = p0[r] + p1[r];
      for (int off = 8; off >= 1; off >>= 1) sum += __shfl_xor(sum, off, 64);
      l_i[r] = l_i[r] * alpha + sum;
      m_i[r] = mnew;
      for (int dt = 0; dt < 8; ++dt) oacc[dt][r] *= alpha;
    }

    // P: C-layout (row=quad*4+r, col=jt*16+l16) -> LDS -> A-layout read
    for (int r = 0; r < 4; ++r) {
      Ps[wave][(quad * 4 + r) * 32 + l16]      = (__bf16)p0[r];
      Ps[wave][(quad * 4 + r) * 32 + 16 + l16] = (__bf16)p1[r];
    }
    __syncthreads();  // orders Ps write->read (uniform trip count across waves)
    bf16x8 pf = *(const bf16x8*)&Ps[wave][l16 * 32 + quad * 8];
    for (int dt = 0; dt < 8; ++dt) {
      bf16x8 vf = *(const bf16x8*)&Vs[(dt * 16 + l16) * 32 + quad * 8];
      oacc[dt] = __builtin_amdgcn_mfma_f32_16x16x32_bf16(pf, vf, oacc[dt], 0, 0, 0);
    }
    __syncthreads();
  }

  for (int r = 0; r < 4; ++r) {
    float inv = 1.0f / l_i[r];
    size_t q = qrow + quad * 4 + r;
    for (int dt = 0; dt < 8; ++dt)
      O[q * (size_t)(NH * HD) + (size_t)h * HD + dt * 16 + l16] = (__bf16)(oacc[dt][r] * inv);
  }
}

extern "C" void kernel_launch(void* const* d_in, const int* in_sizes, int n_in,
                              void* d_out, int out_size, void* d_ws, size_t ws_size,
                              hipStream_t stream) {
  const float* hidden    = (const float*)d_in[0];
  const int*   positions = (const int*)d_in[1];
  const float* Wqkv      = (const float*)d_in[2];
  const float* Wo        = (const float*)d_in[3];
  float* out = (float*)d_out;

  // workspace layout (all 256B aligned); total ~151 MB
  char* p = (char*)d_ws;
  auto alloc = [&](size_t bytes) { char* r = p; p += (bytes + 255) & ~(size_t)255; return r; };
  __bf16* hid_bf = (__bf16*)alloc((size_t)S_LEN * HID * 2);       // 16 MB (reused as attn_out)
  __bf16* wqkvT  = (__bf16*)alloc((size_t)QKV_N * HID * 2);       // 48 MB  [6144][4096]
  __bf16* woT    = (__bf16*)alloc((size_t)HID * HID * 2);         // 32 MB  [4096][4096]
  __bf16* qkv    = (__bf16*)alloc((size_t)S_LEN * QKV_N * 2);     // 24 MB
  __bf16* Qr     = (__bf16*)alloc((size_t)S_LEN * NH * HD * 2);   // 16 MB
  __bf16* Kr     = (__bf16*)alloc((size_t)S_LEN * NKV * HD * 2);  // 4 MB
  __bf16* Vt     = (__bf16*)alloc((size_t)S_LEN * NKV * HD * 2);  // 4 MB
  __bf16* attn   = hid_bf;  // hidden_bf16 dead after GEMM1

  // 1) cast hidden -> bf16
  {
    int n4 = S_LEN * HID / 4;
    cast_bf16_kernel<<<(n4 + 255) / 256, 256, 0, stream>>>((const float4*)hidden, hid_bf, n4);
  }
  // 2) W_qkv^T, W_o^T (cast to bf16)
  transpose_cast_kernel<<<dim3(QKV_N / 32, HID / 32), dim3(32, 8), 0, stream>>>(Wqkv, wqkvT, HID, QKV_N);
  transpose_cast_kernel<<<dim3(HID / 32, HID / 32), dim3(32, 8), 0, stream>>>(Wo, woT, HID, HID);
  // 3) qkv = hidden @ W_qkv  (bf16 out)
  gemm_bt_kernel<__bf16><<<dim3(QKV_N / 128, S_LEN / 128), 256, 0, stream>>>(
      hid_bf, wqkvT, qkv, S_LEN, QKV_N, HID);
  // 4) RoPE -> Qr, Kr
  {
    int total = S_LEN * NQK * 64;
    rope_kernel<<<total / 256, 256, 0, stream>>>(qkv, positions, Qr, Kr);
  }
  // 5) V^T
  transpose_v_kernel<<<dim3(S_LEN / 32, HD / 32, NKV), dim3(32, 8), 0, stream>>>(qkv, Vt);
  // 6) flash attention -> attn (bf16 [S][NH*HD])
  attn_kernel<<<dim3(NH, S_LEN / 64), 256, 0, stream>>>(Qr, Kr, Vt, attn);
  // 7) out = attn @ W_o (fp32 out)
  gemm_bt_kernel<float><<<dim3(HID / 128, S_LEN / 128), 256, 0, stream>>>(
      attn, woT, out, S_LEN, HID, HID);
}

// Round 2
// 648.475 us; speedup vs baseline: 1.1202x; 1.1202x over previous
//
#include <hip/hip_runtime.h>
#include <math.h>

// Problem constants
#define S_LEN 2048
#define HID 4096
#define NH 32
#define NKV 8
#define HD 128
#define QKV_N ((NH + 2*NKV) * HD)   // 6144
#define NQK (NH + NKV)              // 40
static __device__ __constant__ const float SCALE_F = 0.08838834764831845f; // 128^-0.5

typedef __bf16 bf16x8 __attribute__((ext_vector_type(8)));
typedef __bf16 bf16x4 __attribute__((ext_vector_type(4)));
typedef float  f32x4  __attribute__((ext_vector_type(4)));

#define GLD_LDS(gptr, lptr) \
  __builtin_amdgcn_global_load_lds( \
      (const __attribute__((address_space(1))) uint32_t*)(gptr), \
      (__attribute__((address_space(3))) uint32_t*)(lptr), 16, 0, 0)

// ---------- cast fp32 -> bf16 (vectorized) ----------
__global__ void cast_bf16_kernel(const float4* __restrict__ in, __bf16* __restrict__ out, int n4) {
  int i = blockIdx.x * blockDim.x + threadIdx.x;
  if (i >= n4) return;
  float4 v = in[i];
  bf16x4 o = { (__bf16)v.x, (__bf16)v.y, (__bf16)v.z, (__bf16)v.w };
  *(bf16x4*)(out + (size_t)i * 4) = o;
}

// ---------- transpose + cast: in[R][C] fp32 -> out[C][R] bf16 ----------
__global__ void transpose_cast_kernel(const float* __restrict__ in, __bf16* __restrict__ out,
                                      int R, int C) {
  __shared__ float tile[32][33];
  int bx = blockIdx.x * 32;  // col of in
  int by = blockIdx.y * 32;  // row of in
  int tx = threadIdx.x, ty = threadIdx.y;
  for (int i = 0; i < 32; i += 8)
    tile[ty + i][tx] = in[(size_t)(by + ty + i) * C + bx + tx];
  __syncthreads();
  for (int i = 0; i < 32; i += 8)
    out[(size_t)(bx + ty + i) * R + by + tx] = (__bf16)tile[tx][ty + i];
}

// ---------- V transpose: Vt[kvh][d][s] = qkv[s][(NH+NKV)*HD + kvh*HD + d] ----------
__global__ void transpose_v_kernel(const __bf16* __restrict__ qkv, __bf16* __restrict__ Vt) {
  __shared__ __bf16 tile[32][33];
  int kvh = blockIdx.z;
  int sb = blockIdx.x * 32;
  int db = blockIdx.y * 32;
  int tx = threadIdx.x, ty = threadIdx.y;
  const __bf16* src = qkv + (size_t)(NH + NKV) * HD + (size_t)kvh * HD;
  for (int i = 0; i < 32; i += 8)
    tile[ty + i][tx] = src[(size_t)(sb + ty + i) * QKV_N + db + tx];
  __syncthreads();
  for (int i = 0; i < 32; i += 8)
    Vt[((size_t)kvh * HD + db + ty + i) * S_LEN + sb + tx] = tile[tx][ty + i];
}

// ---------- RoPE: split qkv -> Qr [S][NH][HD], Kr [S][NKV][HD] with rotation ----------
__global__ void rope_kernel(const __bf16* __restrict__ qkv, const int* __restrict__ pos,
                            __bf16* __restrict__ Qr, __bf16* __restrict__ Kr) {
  int idx = blockIdx.x * blockDim.x + threadIdx.x;
  int half = idx & 63;         // 0..63
  int t = idx >> 6;
  int hh = t % NQK;
  int s = t / NQK;
  if (s >= S_LEN) return;
  float p = (float)pos[s];
  float inv_freq = powf(10000.0f, -(float)half / 64.0f);
  float ang = p * inv_freq;
  float cs = cosf(ang), sn = sinf(ang);
  const __bf16* src; __bf16* dst;
  if (hh < NH) {
    src = qkv + (size_t)s * QKV_N + (size_t)hh * HD;
    dst = Qr + ((size_t)s * NH + hh) * HD;
  } else {
    int kh = hh - NH;
    src = qkv + (size_t)s * QKV_N + (size_t)NH * HD + (size_t)kh * HD;
    dst = Kr + ((size_t)s * NKV + kh) * HD;
  }
  float x1 = (float)src[half], x2 = (float)src[half + 64];
  dst[half]      = (__bf16)(x1 * cs - x2 * sn);
  dst[half + 64] = (__bf16)(x2 * cs + x1 * sn);
}

// ---------- bf16 MFMA GEMM: C[M][N] = A[M][K] @ Bt[N][K]^T ----------
// 128x128 tile, BK=32, global_load_lds width-16 staging (m97 structure, 874 TF @4096^3).
// C/D layout (verified m89/m91): col=lane&15, row=quad*4+reg.
template <typename OutT>
__global__ __launch_bounds__(256) void gemm_bt_kernel(const __bf16* __restrict__ A,
                                                      const __bf16* __restrict__ Bt,
                                                      OutT* __restrict__ C,
                                                      int M, int N, int K) {
  __shared__ __align__(16) __bf16 As[128 * 32];
  __shared__ __align__(16) __bf16 Bs[128 * 32];
  const int tid = threadIdx.x;
  const int lane = tid & 63;
  const int wave = tid >> 6;
  const int quad = lane >> 4;
  const int l16 = lane & 15;
  const int wm = (wave >> 1) * 64;
  const int wn = (wave & 1) * 64;
  const size_t bm = (size_t)blockIdx.y * 128;
  const size_t bn = (size_t)blockIdx.x * 128;

  f32x4 acc[4][4] = {};

  for (int k0 = 0; k0 < K; k0 += 32) {
    for (int it = 0; it < 2; ++it) {
      int c = it * 256 + tid;          // chunk 0..511, 16B each
      int row = c >> 2, kc = c & 3;
      GLD_LDS(&A[(bm + row) * (size_t)K + k0 + kc * 8], &As[c * 8]);
      GLD_LDS(&Bt[(bn + row) * (size_t)K + k0 + kc * 8], &Bs[c * 8]);
    }
    __syncthreads();
    bf16x8 af[4], bfr[4];
    for (int i = 0; i < 4; ++i) af[i]  = *(const bf16x8*)&As[(wm + i * 16 + l16) * 32 + quad * 8];
    for (int j = 0; j < 4; ++j) bfr[j] = *(const bf16x8*)&Bs[(wn + j * 16 + l16) * 32 + quad * 8];
    for (int i = 0; i < 4; ++i)
      for (int j = 0; j < 4; ++j)
        acc[i][j] = __builtin_amdgcn_mfma_f32_16x16x32_bf16(af[i], bfr[j], acc[i][j], 0, 0, 0);
    __syncthreads();
  }
  for (int i = 0; i < 4; ++i)
    for (int j = 0; j < 4; ++j)
      for (int r = 0; r < 4; ++r) {
        size_t row = bm + wm + i * 16 + quad * 4 + r;
        size_t col = bn + wn + j * 16 + l16;
        C[row * (size_t)N + col] = (OutT)acc[i][j][r];
      }
}

// ---------- flash attention (causal, GQA) ----------
// Flat grid NH * S/64, longest query-blocks first. Block: 256 (4 waves), wave w
// owns queries q0+16w..q0+16w+15. BK=64 keys/iter: QK^T 16 MFMA + PV 16 MFMA.
// LDS padded (Ks +8, Vs/Ps +8) to break power-of-2 bank strides.
// 2 barriers/iter: Ps is per-wave (LDS in-order within a wave -> no 3rd barrier).
#define KP 136   // 272 B row: 68 dwords, %32=4 -> 2 lanes/bank (free)
#define VP 72    // 144 B row: 36 dwords, %32=4 -> free
__global__ __launch_bounds__(256) void attn_kernel(const __bf16* __restrict__ Qr,
                                                   const __bf16* __restrict__ Kr,
                                                   const __bf16* __restrict__ Vt,
                                                   __bf16* __restrict__ O) {
  __shared__ __align__(16) __bf16 Ks[64 * KP];      // [key][d]
  __shared__ __align__(16) __bf16 Vs[128 * VP];     // [d][key]
  __shared__ __align__(16) __bf16 Ps[4][16 * VP];   // per-wave P: [q][key]
  const int bid = blockIdx.x;
  const int h = bid & (NH - 1);
  const int qb = (S_LEN / 64 - 1) - (bid >> 5);     // longest first
  const int kvh = h >> 2;                            // REP = 4
  const int tid = threadIdx.x;
  const int lane = tid & 63, wave = tid >> 6;
  const int quad = lane >> 4, l16 = lane & 15;
  const int q0 = qb * 64;
  const int qrow = q0 + wave * 16;

  bf16x8 qf[4];
  {
    const __bf16* qp = Qr + (size_t)(qrow + l16) * (NH * HD) + (size_t)h * HD + quad * 8;
    for (int kk = 0; kk < 4; ++kk) qf[kk] = *(const bf16x8*)(qp + kk * 32);
  }
  f32x4 oacc[8] = {};
  float m_i[4], l_i[4];
  for (int r = 0; r < 4; ++r) { m_i[r] = -INFINITY; l_i[r] = 0.0f; }

  for (int kb = 0; kb <= q0; kb += 64) {
    // stage K block: 64 rows x 128 d  (1024 x 16B chunks, 4/thread)
    for (int pass = 0; pass < 4; ++pass) {
      int c = pass * 256 + tid;
      int row = c >> 4, c8 = c & 15;
      *(uint4*)&Ks[row * KP + c8 * 8] =
        *(const uint4*)&Kr[(size_t)(kb + row) * (NKV * HD) + (size_t)kvh * HD + c8 * 8];
    }
    // stage V^T block: 128 d x 64 keys (1024 x 16B chunks, 4/thread)
    for (int pass = 0; pass < 4; ++pass) {
      int c = pass * 256 + tid;
      int d = c >> 3, c8 = c & 7;
      *(uint4*)&Vs[d * VP + c8 * 8] =
        *(const uint4*)&Vt[((size_t)kvh * HD + d) * S_LEN + kb + c8 * 8];
    }
    __syncthreads();

    // QK^T: 4 col-tiles x 4 k-chunks
    f32x4 sc[4] = {};
    for (int jt = 0; jt < 4; ++jt)
      for (int kk = 0; kk < 4; ++kk) {
        bf16x8 kf = *(const bf16x8*)&Ks[(jt * 16 + l16) * KP + kk * 32 + quad * 8];
        sc[jt] = __builtin_amdgcn_mfma_f32_16x16x32_bf16(qf[kk], kf, sc[jt], 0, 0, 0);
      }

    const bool masked = (kb == q0);   // wave-uniform: only the diagonal tile masks
    for (int r = 0; r < 4; ++r) {
      float s[4];
      for (int jt = 0; jt < 4; ++jt) s[jt] = sc[jt][r] * SCALE_F;
      if (masked) {
        int qloc = wave * 16 + quad * 4 + r;
        for (int jt = 0; jt < 4; ++jt)
          if (jt * 16 + l16 > qloc) s[jt] = -INFINITY;
      }
      float mx = fmaxf(fmaxf(s[0], s[1]), fmaxf(s[2], s[3]));
      for (int off = 8; off >= 1; off >>= 1) mx = fmaxf(mx, __shfl_xor(mx, off, 64));
      float mnew = fmaxf(m_i[r], mx);
      float alpha = __expf(m_i[r] - mnew);   // first iter: exp(-inf)=0
      float p[4], sum = 0.0f;
      for (int jt = 0; jt < 4; ++jt) { p[jt] = __expf(s[jt] - mnew); sum += p[jt]; }
      for (int off = 8; off >= 1; off >>= 1) sum += __shfl_xor(sum, off, 64);
      l_i[r] = l_i[r] * alpha + sum;
      m_i[r] = mnew;
      for (int dt = 0; dt < 8; ++dt) oacc[dt][r] *= alpha;
      // P write: C-layout (row=quad*4+r, col=jt*16+l16) into per-wave slice
      for (int jt = 0; jt < 4; ++jt)
        Ps[wave][(quad * 4 + r) * VP + jt * 16 + l16] = (__bf16)p[jt];
    }
    // no barrier: each wave reads only its own Ps slice; LDS is in-order per wave
    bf16x8 pf0 = *(const bf16x8*)&Ps[wave][l16 * VP + quad * 8];
    bf16x8 pf1 = *(const bf16x8*)&Ps[wave][l16 * VP + 32 + quad * 8];
    for (int dt = 0; dt < 8; ++dt) {
      bf16x8 vf0 = *(const bf16x8*)&Vs[(dt * 16 + l16) * VP + quad * 8];
      bf16x8 vf1 = *(const bf16x8*)&Vs[(dt * 16 + l16) * VP + 32 + quad * 8];
      oacc[dt] = __builtin_amdgcn_mfma_f32_16x16x32_bf16(pf0, vf0, oacc[dt], 0, 0, 0);
      oacc[dt] = __builtin_amdgcn_mfma_f32_16x16x32_bf16(pf1, vf1, oacc[dt], 0, 0, 0);
    }
    __syncthreads();   // protect Ks/Vs before next stage
  }

  for (int r = 0; r < 4; ++r) {
    float inv = 1.0f / l_i[r];
    size_t q = qrow + quad * 4 + r;
    for (int dt = 0; dt < 8; ++dt)
      O[q * (size_t)(NH * HD) + (size_t)h * HD + dt * 16 + l16] = (__bf16)(oacc[dt][r] * inv);
  }
}

extern "C" void kernel_launch(void* const* d_in, const int* in_sizes, int n_in,
                              void* d_out, int out_size, void* d_ws, size_t ws_size,
                              hipStream_t stream) {
  const float* hidden    = (const float*)d_in[0];
  const int*   positions = (const int*)d_in[1];
  const float* Wqkv      = (const float*)d_in[2];
  const float* Wo        = (const float*)d_in[3];
  float* out = (float*)d_out;

  char* p = (char*)d_ws;
  auto alloc = [&](size_t bytes) { char* r = p; p += (bytes + 255) & ~(size_t)255; return r; };
  __bf16* hid_bf = (__bf16*)alloc((size_t)S_LEN * HID * 2);       // 16 MB (reused as attn_out)
  __bf16* wqkvT  = (__bf16*)alloc((size_t)QKV_N * HID * 2);       // 48 MB  [6144][4096]
  __bf16* woT    = (__bf16*)alloc((size_t)HID * HID * 2);         // 32 MB  [4096][4096]
  __bf16* qkv    = (__bf16*)alloc((size_t)S_LEN * QKV_N * 2);     // 24 MB
  __bf16* Qr     = (__bf16*)alloc((size_t)S_LEN * NH * HD * 2);   // 16 MB
  __bf16* Kr     = (__bf16*)alloc((size_t)S_LEN * NKV * HD * 2);  // 4 MB
  __bf16* Vt     = (__bf16*)alloc((size_t)S_LEN * NKV * HD * 2);  // 4 MB
  __bf16* attn   = hid_bf;  // hidden_bf16 dead after GEMM1

  {
    int n4 = S_LEN * HID / 4;
    cast_bf16_kernel<<<(n4 + 255) / 256, 256, 0, stream>>>((const float4*)hidden, hid_bf, n4);
  }
  transpose_cast_kernel<<<dim3(QKV_N / 32, HID / 32), dim3(32, 8), 0, stream>>>(Wqkv, wqkvT, HID, QKV_N);
  transpose_cast_kernel<<<dim3(HID / 32, HID / 32), dim3(32, 8), 0, stream>>>(Wo, woT, HID, HID);
  gemm_bt_kernel<__bf16><<<dim3(QKV_N / 128, S_LEN / 128), 256, 0, stream>>>(
      hid_bf, wqkvT, qkv, S_LEN, QKV_N, HID);
  {
    int total = S_LEN * NQK * 64;
    rope_kernel<<<total / 256, 256, 0, stream>>>(qkv, positions, Qr, Kr);
  }
  transpose_v_kernel<<<dim3(S_LEN / 32, HD / 32, NKV), dim3(32, 8), 0, stream>>>(qkv, Vt);
  attn_kernel<<<NH * (S_LEN / 64), 256, 0, stream>>>(Qr, Kr, Vt, attn);
  gemm_bt_kernel<float><<<dim3(HID / 128, S_LEN / 128), 256, 0, stream>>>(
      attn, woT, out, S_LEN, HID, HID);
}

// Round 3
// 618.920 us; speedup vs baseline: 1.1737x; 1.0478x over previous
//
#include <hip/hip_runtime.h>
#include <math.h>

// Problem constants
#define S_LEN 2048
#define HID 4096
#define NH 32
#define NKV 8
#define HD 128
#define QKV_N ((NH + 2*NKV) * HD)   // 6144
#define NQK (NH + NKV)              // 40
static __device__ __constant__ const float SCALE_F = 0.08838834764831845f; // 128^-0.5

typedef __bf16 bf16x8 __attribute__((ext_vector_type(8)));
typedef __bf16 bf16x4 __attribute__((ext_vector_type(4)));
typedef float  f32x4  __attribute__((ext_vector_type(4)));

#define GLD_LDS(gptr, lptr) \
  __builtin_amdgcn_global_load_lds( \
      (const __attribute__((address_space(1))) uint32_t*)(gptr), \
      (__attribute__((address_space(3))) uint32_t*)(lptr), 16, 0, 0)

// ---------- cast fp32 -> bf16 (vectorized) ----------
__global__ void cast_bf16_kernel(const float4* __restrict__ in, __bf16* __restrict__ out, int n4) {
  int i = blockIdx.x * blockDim.x + threadIdx.x;
  if (i >= n4) return;
  float4 v = in[i];
  bf16x4 o = { (__bf16)v.x, (__bf16)v.y, (__bf16)v.z, (__bf16)v.w };
  *(bf16x4*)(out + (size_t)i * 4) = o;
}

// ---------- transpose + cast: in[R][C] fp32 -> out[C][R] bf16 ----------
__global__ void transpose_cast_kernel(const float* __restrict__ in, __bf16* __restrict__ out,
                                      int R, int C) {
  __shared__ float tile[32][33];
  int bx = blockIdx.x * 32;  // col of in
  int by = blockIdx.y * 32;  // row of in
  int tx = threadIdx.x, ty = threadIdx.y;
  for (int i = 0; i < 32; i += 8)
    tile[ty + i][tx] = in[(size_t)(by + ty + i) * C + bx + tx];
  __syncthreads();
  for (int i = 0; i < 32; i += 8)
    out[(size_t)(bx + ty + i) * R + by + tx] = (__bf16)tile[tx][ty + i];
}

// ---------- V transpose: Vt[kvh][d][s] = qkv[s][(NH+NKV)*HD + kvh*HD + d] ----------
__global__ void transpose_v_kernel(const __bf16* __restrict__ qkv, __bf16* __restrict__ Vt) {
  __shared__ __bf16 tile[32][33];
  int kvh = blockIdx.z;
  int sb = blockIdx.x * 32;
  int db = blockIdx.y * 32;
  int tx = threadIdx.x, ty = threadIdx.y;
  const __bf16* src = qkv + (size_t)(NH + NKV) * HD + (size_t)kvh * HD;
  for (int i = 0; i < 32; i += 8)
    tile[ty + i][tx] = src[(size_t)(sb + ty + i) * QKV_N + db + tx];
  __syncthreads();
  for (int i = 0; i < 32; i += 8)
    Vt[((size_t)kvh * HD + db + ty + i) * S_LEN + sb + tx] = tile[tx][ty + i];
}

// ---------- RoPE: split qkv -> Qr [S][NH][HD], Kr [S][NKV][HD] with rotation ----------
__global__ void rope_kernel(const __bf16* __restrict__ qkv, const int* __restrict__ pos,
                            __bf16* __restrict__ Qr, __bf16* __restrict__ Kr) {
  int idx = blockIdx.x * blockDim.x + threadIdx.x;
  int half = idx & 63;         // 0..63
  int t = idx >> 6;
  int hh = t % NQK;
  int s = t / NQK;
  if (s >= S_LEN) return;
  float p = (float)pos[s];
  // inv_freq = 10000^(-half/64) = exp2(-half * log2(10000)/64)
  float inv_freq = exp2f((float)half * -0.2076205059304601f);
  float ang = p * inv_freq;
  float cs = cosf(ang), sn = sinf(ang);
  const __bf16* src; __bf16* dst;
  if (hh < NH) {
    src = qkv + (size_t)s * QKV_N + (size_t)hh * HD;
    dst = Qr + ((size_t)s * NH + hh) * HD;
  } else {
    int kh = hh - NH;
    src = qkv + (size_t)s * QKV_N + (size_t)NH * HD + (size_t)kh * HD;
    dst = Kr + ((size_t)s * NKV + kh) * HD;
  }
  float x1 = (float)src[half], x2 = (float)src[half + 64];
  dst[half]      = (__bf16)(x1 * cs - x2 * sn);
  dst[half + 64] = (__bf16)(x2 * cs + x1 * sn);
}

// ---------- bf16 MFMA GEMM: C[M][N] = A[M][K] @ Bt[N][K]^T ----------
// 128x128 tile, BK=32, global_load_lds width-16 staging (m97 structure).
template <typename OutT>
__global__ __launch_bounds__(256) void gemm_bt_kernel(const __bf16* __restrict__ A,
                                                      const __bf16* __restrict__ Bt,
                                                      OutT* __restrict__ C,
                                                      int M, int N, int K) {
  __shared__ __align__(16) __bf16 As[128 * 32];
  __shared__ __align__(16) __bf16 Bs[128 * 32];
  const int tid = threadIdx.x;
  const int lane = tid & 63;
  const int wave = tid >> 6;
  const int quad = lane >> 4;
  const int l16 = lane & 15;
  const int wm = (wave >> 1) * 64;
  const int wn = (wave & 1) * 64;
  const size_t bm = (size_t)blockIdx.y * 128;
  const size_t bn = (size_t)blockIdx.x * 128;

  f32x4 acc[4][4] = {};

  for (int k0 = 0; k0 < K; k0 += 32) {
    for (int it = 0; it < 2; ++it) {
      int c = it * 256 + tid;          // chunk 0..511, 16B each
      int row = c >> 2, kc = c & 3;
      GLD_LDS(&A[(bm + row) * (size_t)K + k0 + kc * 8], &As[c * 8]);
      GLD_LDS(&Bt[(bn + row) * (size_t)K + k0 + kc * 8], &Bs[c * 8]);
    }
    __syncthreads();
    bf16x8 af[4], bfr[4];
    for (int i = 0; i < 4; ++i) af[i]  = *(const bf16x8*)&As[(wm + i * 16 + l16) * 32 + quad * 8];
    for (int j = 0; j < 4; ++j) bfr[j] = *(const bf16x8*)&Bs[(wn + j * 16 + l16) * 32 + quad * 8];
    for (int i = 0; i < 4; ++i)
      for (int j = 0; j < 4; ++j)
        acc[i][j] = __builtin_amdgcn_mfma_f32_16x16x32_bf16(af[i], bfr[j], acc[i][j], 0, 0, 0);
    __syncthreads();
  }
  for (int i = 0; i < 4; ++i)
    for (int j = 0; j < 4; ++j)
      for (int r = 0; r < 4; ++r) {
        size_t row = bm + wm + i * 16 + quad * 4 + r;
        size_t col = bn + wn + j * 16 + l16;
        C[row * (size_t)N + col] = (OutT)acc[i][j][r];
      }
}

// ---------- flash attention v3 (causal, GQA) ----------
// Transposed-scores formulation: sc = MFMA(K-frag, Q-frag) -> row=key, col=q(=l16).
// Softmax row-reduction = in-lane tree over 16 regs + 2 quad shuffles.
// PV: O^T = V^T · P^T (A = Vs[d][key], B = Ps[q][key]). Epilogue transposes O^T
// through per-wave LDS scratch to get coalesced stores.
// LDS: unpadded Ks(16K)+Vs(16K)+Ps(8K) = 40960 B -> exactly 4 blocks/CU.
// Bank conflicts: XOR-swizzle 16B chunks by (row&7) / (l16&7).
__global__ __launch_bounds__(256, 4) void attn_kernel(const __bf16* __restrict__ Qr,
                                                      const __bf16* __restrict__ Kr,
                                                      const __bf16* __restrict__ Vt,
                                                      __bf16* __restrict__ O) {
  __shared__ __align__(16) char smem[40960];
  __bf16* Ks = (__bf16*)smem;              // [64 key][128 d], 16B chunks swizzled
  __bf16* Vs = (__bf16*)(smem + 16384);    // [128 d][64 key], swizzled
  __bf16* Ps = (__bf16*)(smem + 32768);    // [4 wave][16 q][64 key], swizzled

  const int bid = blockIdx.x;
  const int h = bid & (NH - 1);
  const int qb = (S_LEN / 64 - 1) - (bid >> 5);     // longest first
  const int kvh = h >> 2;                            // REP = 4
  const int tid = threadIdx.x;
  const int lane = tid & 63, wave = tid >> 6;
  const int quad = lane >> 4, l16 = lane & 15;
  const int sw = l16 & 7;                            // swizzle key
  const int q0 = qb * 64;

  // Q fragments (B-operand: n=l16 -> q, k=quad*8+j -> d)
  bf16x8 qf[4];
  {
    const __bf16* qp = Qr + (size_t)(q0 + wave * 16 + l16) * (NH * HD) + (size_t)h * HD + quad * 8;
    for (int kk = 0; kk < 4; ++kk) qf[kk] = *(const bf16x8*)(qp + kk * 32);
  }
  f32x4 oacc[8] = {};          // O^T: row=d_local(quad*4+r), col=q(l16)
  float m2 = -INFINITY, l_i = 0.0f;   // per-q state (q = l16), base-2 domain
  const float C2 = SCALE_F * 1.4426950408889634f;

  for (int kb = 0; kb <= q0; kb += 64) {
    // stage K: 64 key x 128 d (1024 chunks of 16B)
    for (int pass = 0; pass < 4; ++pass) {
      int c = pass * 256 + tid;
      int row = c >> 4, ch = c & 15;
      int chs = ch ^ (row & 7);
      *(uint4*)&Ks[row * 128 + chs * 8] =
        *(const uint4*)&Kr[(size_t)(kb + row) * (NKV * HD) + (size_t)kvh * HD + ch * 8];
    }
    // stage V^T: 128 d x 64 key (1024 chunks)
    for (int pass = 0; pass < 4; ++pass) {
      int c = pass * 256 + tid;
      int d = c >> 3, ch = c & 7;
      int chs = ch ^ (d & 7);
      *(uint4*)&Vs[d * 64 + chs * 8] =
        *(const uint4*)&Vt[((size_t)kvh * HD + d) * S_LEN + kb + ch * 8];
    }
    __syncthreads();

    // QK^T transposed: sc[jt] row=key_local(quad*4+r), col=q(l16)
    f32x4 sc[4] = {};
    for (int jt = 0; jt < 4; ++jt)
      for (int kk = 0; kk < 4; ++kk) {
        bf16x8 kf = *(const bf16x8*)&Ks[(jt * 16 + l16) * 128 + ((kk * 4 + quad) ^ sw) * 8];
        sc[jt] = __builtin_amdgcn_mfma_f32_16x16x32_bf16(kf, qf[kk], sc[jt], 0, 0, 0);
      }

    float s[16];
    for (int jt = 0; jt < 4; ++jt)
      for (int r = 0; r < 4; ++r) s[jt * 4 + r] = sc[jt][r];
    if (kb == q0) {                      // diagonal tile: mask key > q
      int qloc = wave * 16 + l16;
      for (int jt = 0; jt < 4; ++jt)
        for (int r = 0; r < 4; ++r)
          if (jt * 16 + quad * 4 + r > qloc) s[jt * 4 + r] = -INFINITY;
    }
    // in-lane max over 16 keys + 2 quad shuffles
    float mx = s[0];
    for (int i = 1; i < 16; ++i) mx = fmaxf(mx, s[i]);
    mx = fmaxf(mx, __shfl_xor(mx, 16, 64));
    mx = fmaxf(mx, __shfl_xor(mx, 32, 64));
    float m2new = fmaxf(m2, mx * C2);
    float alpha = exp2f(m2 - m2new);
    float pv[16], sum = 0.0f;
    for (int i = 0; i < 16; ++i) { pv[i] = exp2f(fmaf(s[i], C2, -m2new)); sum += pv[i]; }
    sum += __shfl_xor(sum, 16, 64);
    sum += __shfl_xor(sum, 32, 64);
    l_i = l_i * alpha + sum;
    m2 = m2new;
    for (int dt = 0; dt < 8; ++dt) oacc[dt] *= alpha;

    // store P^T as Ps[q][key] (per-wave slice, swizzled); q=l16, key=jt*16+quad*4+r
    __bf16* pw = Ps + wave * 1024 + l16 * 64;
    for (int jt = 0; jt < 4; ++jt) {
      bf16x4 pk = { (__bf16)pv[jt*4+0], (__bf16)pv[jt*4+1], (__bf16)pv[jt*4+2], (__bf16)pv[jt*4+3] };
      int chunk = jt * 2 + (quad >> 1);
      *(bf16x4*)&pw[((chunk ^ sw) * 8) + (quad & 1) * 4] = pk;
    }
    // no barrier: wave reads only its own Ps slice (LDS in-order per wave)
    for (int half = 0; half < 2; ++half) {
      bf16x8 pf = *(const bf16x8*)&pw[((half * 4 + quad) ^ sw) * 8];
      for (int dt = 0; dt < 8; ++dt) {
        bf16x8 vf = *(const bf16x8*)&Vs[(dt * 16 + l16) * 64 + ((half * 4 + quad) ^ sw) * 8];
        oacc[dt] = __builtin_amdgcn_mfma_f32_16x16x32_bf16(vf, pf, oacc[dt], 0, 0, 0);
      }
    }
    __syncthreads();   // protect Ks/Vs for next stage (and scratch reuse after loop)
  }

  // epilogue: O^T (d rows, q cols) -> per-wave LDS scratch -> coalesced O stores
  float* scr = (float*)smem + wave * 2112;          // 16 q rows x 132 floats
  float inv = 1.0f / l_i;
  for (int dt = 0; dt < 8; ++dt) {
    f32x4 v = oacc[dt] * inv;
    *(f32x4*)&scr[l16 * 132 + dt * 16 + quad * 4] = v;
  }
  // same-wave read-back, transposed
  for (int it = 0; it < 4; ++it) {
    int c = it * 64 + lane;
    int row = c >> 4, ch = c & 15;
    const float* sp = &scr[row * 132 + ch * 8];
    f32x4 a = *(const f32x4*)sp;
    f32x4 b = *(const f32x4*)(sp + 4);
    bf16x8 o = { (__bf16)a[0], (__bf16)a[1], (__bf16)a[2], (__bf16)a[3],
                 (__bf16)b[0], (__bf16)b[1], (__bf16)b[2], (__bf16)b[3] };
    *(bf16x8*)&O[(size_t)(q0 + wave * 16 + row) * (NH * HD) + (size_t)h * HD + ch * 8] = o;
  }
}

extern "C" void kernel_launch(void* const* d_in, const int* in_sizes, int n_in,
                              void* d_out, int out_size, void* d_ws, size_t ws_size,
                              hipStream_t stream) {
  const float* hidden    = (const float*)d_in[0];
  const int*   positions = (const int*)d_in[1];
  const float* Wqkv      = (const float*)d_in[2];
  const float* Wo        = (const float*)d_in[3];
  float* out = (float*)d_out;

  char* p = (char*)d_ws;
  auto alloc = [&](size_t bytes) { char* r = p; p += (bytes + 255) & ~(size_t)255; return r; };
  __bf16* hid_bf = (__bf16*)alloc((size_t)S_LEN * HID * 2);       // 16 MB (reused as attn_out)
  __bf16* wqkvT  = (__bf16*)alloc((size_t)QKV_N * HID * 2);       // 48 MB  [6144][4096]
  __bf16* woT    = (__bf16*)alloc((size_t)HID * HID * 2);         // 32 MB  [4096][4096]
  __bf16* qkv    = (__bf16*)alloc((size_t)S_LEN * QKV_N * 2);     // 24 MB
  __bf16* Qr     = (__bf16*)alloc((size_t)S_LEN * NH * HD * 2);   // 16 MB
  __bf16* Kr     = (__bf16*)alloc((size_t)S_LEN * NKV * HD * 2);  // 4 MB
  __bf16* Vt     = (__bf16*)alloc((size_t)S_LEN * NKV * HD * 2);  // 4 MB
  __bf16* attn   = hid_bf;  // hidden_bf16 dead after GEMM1

  {
    int n4 = S_LEN * HID / 4;
    cast_bf16_kernel<<<(n4 + 255) / 256, 256, 0, stream>>>((const float4*)hidden, hid_bf, n4);
  }
  transpose_cast_kernel<<<dim3(QKV_N / 32, HID / 32), dim3(32, 8), 0, stream>>>(Wqkv, wqkvT, HID, QKV_N);
  transpose_cast_kernel<<<dim3(HID / 32, HID / 32), dim3(32, 8), 0, stream>>>(Wo, woT, HID, HID);
  gemm_bt_kernel<__bf16><<<dim3(QKV_N / 128, S_LEN / 128), 256, 0, stream>>>(
      hid_bf, wqkvT, qkv, S_LEN, QKV_N, HID);
  {
    int total = S_LEN * NQK * 64;
    rope_kernel<<<total / 256, 256, 0, stream>>>(qkv, positions, Qr, Kr);
  }
  transpose_v_kernel<<<dim3(S_LEN / 32, HD / 32, NKV), dim3(32, 8), 0, stream>>>(qkv, Vt);
  attn_kernel<<<NH * (S_LEN / 64), 256, 0, stream>>>(Qr, Kr, Vt, attn);
  gemm_bt_kernel<float><<<dim3(HID / 128, S_LEN / 128), 256, 0, stream>>>(
      attn, woT, out, S_LEN, HID, HID);
}